// Round 2
// baseline (136.531 us; speedup 1.0000x reference)
//
#include <hip/hip_runtime.h>

typedef float vf4 __attribute__((ext_vector_type(4)));

#define MASKV (-1000000.0f)
#define LOG2E 1.4426950408889634f
#define TWO_LOG2E 2.8853900817779268f

__device__ __forceinline__ float fexp2(float x) { return __builtin_amdgcn_exp2f(x); }
__device__ __forceinline__ float frcp(float x) { return __builtin_amdgcn_rcpf(x); }

// ---------------------------------------------------------------------------
// Kernel 1: projections. C(4096x256): rows 0..2047 = queries@Wq^T -> Qp,
// rows 2048..4095 = keyes@Wk^T -> Kp. Result pre-scaled by 2*log2(e) so the
// scores kernel can feed exp2 directly (tanh(x) = 1 - 2/(exp2(2x*log2e)+1)).
__global__ __launch_bounds__(256) void proj_kernel(
    const float* __restrict__ queries, const float* __restrict__ keyes,
    const float* __restrict__ Wq, const float* __restrict__ Wk,
    float* __restrict__ Qp, float* __restrict__ Kp) {
  __shared__ alignas(16) float At[16 * 68];  // [k][m]
  __shared__ alignas(16) float Bt[16 * 68];  // [k][n]
  const int t = threadIdx.x;
  const int m0 = blockIdx.x * 64;
  const int n0 = blockIdx.y * 64;
  const bool isQ = (m0 < 2048);
  const float* X = isQ ? queries : keyes;
  const float* W = isQ ? Wq : Wk;
  float* C = isQ ? Qp : Kp;
  const int mb = isQ ? m0 : (m0 - 2048);

  const int lm = t >> 2;           // 0..63 row
  const int lq = t & 3;            // 0..3 float4 within 16-wide chunk
  const int mm4 = (t & 15) * 4;
  const int nn4 = (t >> 4) * 4;

  float acc[4][4] = {};
  for (int kc = 0; kc < 256; kc += 16) {
    __syncthreads();
    vf4 xa = *(const vf4*)&X[(mb + lm) * 256 + kc + lq * 4];
    vf4 wb = *(const vf4*)&W[(n0 + lm) * 256 + kc + lq * 4];
#pragma unroll
    for (int c = 0; c < 4; ++c) {
      At[(lq * 4 + c) * 68 + lm] = xa[c];
      Bt[(lq * 4 + c) * 68 + lm] = wb[c];
    }
    __syncthreads();
#pragma unroll
    for (int kk = 0; kk < 16; ++kk) {
      vf4 a4 = *(const vf4*)&At[kk * 68 + mm4];
      vf4 b4 = *(const vf4*)&Bt[kk * 68 + nn4];
#pragma unroll
      for (int i = 0; i < 4; ++i)
#pragma unroll
        for (int j = 0; j < 4; ++j) acc[i][j] += a4[i] * b4[j];
    }
  }
#pragma unroll
  for (int i = 0; i < 4; ++i) {
    vf4 o = {acc[i][0] * TWO_LOG2E, acc[i][1] * TWO_LOG2E,
             acc[i][2] * TWO_LOG2E, acc[i][3] * TWO_LOG2E};
    *(vf4*)&C[(mb + mm4 + i) * 256 + n0 + nn4] = o;
  }
}

// ---------------------------------------------------------------------------
// Kernel 2 (dominant, trans-bound): fused scores + mask + softmax(axis=i).
// Block = (b, 8 j-columns) x full i=256 -> softmax over i stays in-block.
// Thread: 4 i (ti + 64r) x 2 j (2*tj + jj). k/wv LDS reads are wave-uniform
// broadcasts; Qs stride 33 -> conflict-free scalar reads.
// score = Swv - 2 * sum_h wv[h] / (exp2(q'+k') + 1), q',k' pre-scaled.
__global__ __launch_bounds__(256) void scores_softmax_kernel(
    const float* __restrict__ Qp, const float* __restrict__ Kp,
    const float* __restrict__ Wv, const int* __restrict__ valid_lens,
    float* __restrict__ WT) {
  __shared__ float Qs[256 * 33 + 8];  // ~33.8 KB, stride 33 (odd: no conflicts)
  __shared__ float Ks[8 * 33];
  __shared__ alignas(16) float wvs[256];
  const int t = threadIdx.x;
  const int b = blockIdx.y;
  const int j0 = blockIdx.x * 8;
  const int ti = t & 63;   // lane = i low bits
  const int tj = t >> 6;   // 0..3 -> j pair {j0+2tj, j0+2tj+1}

  if (t < 64) *(vf4*)&wvs[t * 4] = *(const vf4*)&Wv[t * 4];
  __syncthreads();

  float Swv;  // sum_h wv[h]
  {
    vf4 w4 = *(const vf4*)&wvs[ti * 4];
    float sw = w4[0] + w4[1] + w4[2] + w4[3];
#pragma unroll
    for (int off = 1; off < 64; off <<= 1) sw += __shfl_xor(sw, off, 64);
    Swv = sw;
  }

  float acc0[4] = {0.f, 0.f, 0.f, 0.f};
  float acc1[4] = {0.f, 0.f, 0.f, 0.f};
  const int qr = t >> 2;          // 0..63 staging row group
  const int qc = (t & 3) * 8;     // staging col

  for (int hc = 0; hc < 8; ++hc) {
    __syncthreads();
    // stage Q tile (256 i x 32 h) and K tile (8 j x 32 h)
#pragma unroll
    for (int s = 0; s < 4; ++s) {
      const int i = s * 64 + qr;
      const float* src = &Qp[((b << 8) + i) * 256 + hc * 32 + qc];
      vf4 a = *(const vf4*)src;
      vf4 bb = *(const vf4*)(src + 4);
      float* q = &Qs[i * 33 + qc];
      q[0] = a[0]; q[1] = a[1]; q[2] = a[2]; q[3] = a[3];
      q[4] = bb[0]; q[5] = bb[1]; q[6] = bb[2]; q[7] = bb[3];
    }
    if (t < 64) {
      const int jj = t >> 3, c = (t & 7) * 4;
      vf4 kv = *(const vf4*)&Kp[((b << 8) + j0 + jj) * 256 + hc * 32 + c];
      float* kd = &Ks[jj * 33 + c];
      kd[0] = kv[0]; kd[1] = kv[1]; kd[2] = kv[2]; kd[3] = kv[3];
    }
    __syncthreads();
#pragma unroll
    for (int hh = 0; hh < 8; ++hh) {
      vf4 wv4 = *(const vf4*)&wvs[hc * 32 + hh * 4];
      float k0[4], k1[4];
#pragma unroll
      for (int c = 0; c < 4; ++c) {
        k0[c] = Ks[(tj * 2 + 0) * 33 + hh * 4 + c];  // wave-uniform broadcast
        k1[c] = Ks[(tj * 2 + 1) * 33 + hh * 4 + c];
      }
#pragma unroll
      for (int r = 0; r < 4; ++r) {
        const float* qp = &Qs[(ti + 64 * r) * 33 + hh * 4];
#pragma unroll
        for (int c = 0; c < 4; ++c) {
          const float qv = qp[c];
          acc0[r] += wv4[c] * frcp(fexp2(qv + k0[c]) + 1.0f);
          acc1[r] += wv4[c] * frcp(fexp2(qv + k1[c]) + 1.0f);
        }
      }
    }
  }

  const int len = valid_lens[b];
#pragma unroll
  for (int jj = 0; jj < 2; ++jj) {
    const int j = j0 + tj * 2 + jj;
    const bool masked = (j >= len);  // uniform within the wave
    float sc[4];
#pragma unroll
    for (int r = 0; r < 4; ++r) {
      const float a = (jj == 0) ? acc0[r] : acc1[r];
      sc[r] = masked ? MASKV : (Swv - 2.0f * a);
    }
    // softmax over i: 64 lanes x 4 regs = all 256 i in this wave
    float m = fmaxf(fmaxf(sc[0], sc[1]), fmaxf(sc[2], sc[3]));
#pragma unroll
    for (int off = 1; off < 64; off <<= 1) m = fmaxf(m, __shfl_xor(m, off, 64));
    float e[4], es = 0.f;
#pragma unroll
    for (int r = 0; r < 4; ++r) { e[r] = fexp2((sc[r] - m) * LOG2E); es += e[r]; }
#pragma unroll
    for (int off = 1; off < 64; off <<= 1) es += __shfl_xor(es, off, 64);
    const float rr = frcp(es);
    float* dst = &WT[((b << 8) + j) << 8];
#pragma unroll
    for (int r = 0; r < 4; ++r) dst[ti + 64 * r] = e[r] * rr;
  }
}

// ---------------------------------------------------------------------------
// Kernel 3: out[b,i,d] = sum_j WT[b][j][i] * V[b][j][d]. Both operands are
// already k(=j)-major -> straight b128 staging, no transpose. 128 threads,
// tile 32(i) x 64(d), 4x4 per thread, j chunks of 32. Grid 8x4x8 = 256.
__global__ __launch_bounds__(128) void out_kernel(
    const float* __restrict__ WT, const float* __restrict__ V,
    float* __restrict__ out) {
  __shared__ alignas(16) float As[32 * 36];  // [j][i]
  __shared__ alignas(16) float Bs[32 * 68];  // [j][d]
  const int t = threadIdx.x;
  const int b = blockIdx.z;
  const int i0 = blockIdx.x * 32;
  const int d0 = blockIdx.y * 64;
  const int tm = t & 7;    // m = i0 + tm*4 + i
  const int tn = t >> 3;   // 0..15, n = d0 + tn*4 + j
  const int sr = t >> 2;   // staging row 0..31
  const int sc4 = (t & 3) * 4;
  float acc[4][4] = {};
  for (int jc = 0; jc < 8; ++jc) {
    __syncthreads();
    const int jbase = jc * 32;
#pragma unroll
    for (int s = 0; s < 2; ++s) {
      const int col = sc4 + s * 16;
      *(vf4*)&As[sr * 36 + col] =
          *(const vf4*)&WT[((b << 8) + jbase + sr) * 256 + i0 + col];
    }
#pragma unroll
    for (int s = 0; s < 4; ++s) {
      const int col = sc4 + s * 16;
      *(vf4*)&Bs[sr * 68 + col] =
          *(const vf4*)&V[((b << 8) + jbase + sr) * 256 + d0 + col];
    }
    __syncthreads();
#pragma unroll
    for (int kk = 0; kk < 32; ++kk) {
      vf4 a4 = *(const vf4*)&As[kk * 36 + tm * 4];
      vf4 b4 = *(const vf4*)&Bs[kk * 68 + tn * 4];
#pragma unroll
      for (int i = 0; i < 4; ++i)
#pragma unroll
        for (int j = 0; j < 4; ++j) acc[i][j] += a4[i] * b4[j];
    }
  }
#pragma unroll
  for (int i = 0; i < 4; ++i) {
    vf4 o = {acc[i][0], acc[i][1], acc[i][2], acc[i][3]};
    *(vf4*)&out[((b << 8) + i0 + tm * 4 + i) * 256 + d0 + tn * 4] = o;
  }
}

// ---------------------------------------------------------------------------
extern "C" void kernel_launch(void* const* d_in, const int* in_sizes, int n_in,
                              void* d_out, int out_size, void* d_ws, size_t ws_size,
                              hipStream_t stream) {
  const float* queries = (const float*)d_in[0];
  const float* keyes = (const float*)d_in[1];
  const float* values = (const float*)d_in[2];
  const int* valid_lens = (const int*)d_in[3];
  const float* Wq = (const float*)d_in[4];
  const float* Wk = (const float*)d_in[5];
  const float* Wv = (const float*)d_in[6];
  float* out = (float*)d_out;

  float* Qp = (float*)d_ws;        // 8*256*256 floats (2 MB)
  float* Kp = Qp + 524288;         // 2 MB
  float* WT = Kp + 524288;         // 2 MB, layout [b][j][i]

  proj_kernel<<<dim3(64, 4), 256, 0, stream>>>(queries, keyes, Wq, Wk, Qp, Kp);
  scores_softmax_kernel<<<dim3(32, 8), 256, 0, stream>>>(Qp, Kp, Wv, valid_lens, WT);
  out_kernel<<<dim3(8, 4, 8), 128, 0, stream>>>(WT, values, out);
}

// Round 3
// 125.404 us; speedup vs baseline: 1.0887x; 1.0887x over previous
//
#include <hip/hip_runtime.h>

typedef float vf4 __attribute__((ext_vector_type(4)));
typedef float vf2 __attribute__((ext_vector_type(2)));

#define MASKV (-1000000.0f)
#define LOG2E 1.4426950408889634f
#define TWO_LOG2E 2.8853900817779268f

__device__ __forceinline__ float fexp2(float x) { return __builtin_amdgcn_exp2f(x); }
__device__ __forceinline__ float frcp(float x) { return __builtin_amdgcn_rcpf(x); }

// ---------------------------------------------------------------------------
// Kernel 1: projections. C(4096x256): rows 0..2047 = queries@Wq^T -> Qp,
// rows 2048..4095 = keyes@Wk^T -> Kp. Pre-scaled by 2*log2(e) so scores can
// feed exp2 directly (tanh(x) = 1 - 2/(exp2(2x*log2e)+1)).
__global__ __launch_bounds__(256) void proj_kernel(
    const float* __restrict__ queries, const float* __restrict__ keyes,
    const float* __restrict__ Wq, const float* __restrict__ Wk,
    float* __restrict__ Qp, float* __restrict__ Kp) {
  __shared__ alignas(16) float At[16 * 68];  // [k][m]
  __shared__ alignas(16) float Bt[16 * 68];  // [k][n]
  const int t = threadIdx.x;
  const int m0 = blockIdx.x * 64;
  const int n0 = blockIdx.y * 64;
  const bool isQ = (m0 < 2048);
  const float* X = isQ ? queries : keyes;
  const float* W = isQ ? Wq : Wk;
  float* C = isQ ? Qp : Kp;
  const int mb = isQ ? m0 : (m0 - 2048);

  const int lm = t >> 2;
  const int lq = t & 3;
  const int mm4 = (t & 15) * 4;
  const int nn4 = (t >> 4) * 4;

  float acc[4][4] = {};
  for (int kc = 0; kc < 256; kc += 16) {
    __syncthreads();
    vf4 xa = *(const vf4*)&X[(mb + lm) * 256 + kc + lq * 4];
    vf4 wb = *(const vf4*)&W[(n0 + lm) * 256 + kc + lq * 4];
#pragma unroll
    for (int c = 0; c < 4; ++c) {
      At[(lq * 4 + c) * 68 + lm] = xa[c];
      Bt[(lq * 4 + c) * 68 + lm] = wb[c];
    }
    __syncthreads();
#pragma unroll
    for (int kk = 0; kk < 16; ++kk) {
      vf4 a4 = *(const vf4*)&At[kk * 68 + mm4];
      vf4 b4 = *(const vf4*)&Bt[kk * 68 + nn4];
#pragma unroll
      for (int i = 0; i < 4; ++i)
#pragma unroll
        for (int j = 0; j < 4; ++j) acc[i][j] += a4[i] * b4[j];
    }
  }
#pragma unroll
  for (int i = 0; i < 4; ++i) {
    vf4 o = {acc[i][0] * TWO_LOG2E, acc[i][1] * TWO_LOG2E,
             acc[i][2] * TWO_LOG2E, acc[i][3] * TWO_LOG2E};
    *(vf4*)&C[(mb + mm4 + i) * 256 + n0 + nn4] = o;
  }
}

// ---------------------------------------------------------------------------
// Kernel 2 (dominant, trans-bound): partial scores, h-split x4 for occupancy.
// Block = 32i x 64j x 64h, grid 8it x 4hp x 4j x 8b = 1024 blocks -> 16
// waves/CU. Per thread 2i x 4j. K staged transposed [h][j]: k-frag b128 reads
// are 128B-contiguous per wave (conflict-free). P[hp][b][j][i] += partial.
__global__ __launch_bounds__(256) void scores_part_kernel(
    const float* __restrict__ Qp, const float* __restrict__ Kp,
    const float* __restrict__ Wv, float* __restrict__ P) {
  __shared__ alignas(16) float Qs[32 * 36];  // [i][h], 144B row (16B-aligned)
  __shared__ alignas(16) float Kt[32 * 68];  // [h][j], 272B row
  __shared__ alignas(16) float wvs[64];
  const int t = threadIdx.x;
  const int it = blockIdx.x & 7;
  const int hp = blockIdx.x >> 3;
  const int i0 = it * 32;
  const int h0 = hp * 64;
  const int j0 = blockIdx.y * 64;
  const int b = blockIdx.z;

  if (t < 16) *(vf4*)&wvs[t * 4] = *(const vf4*)&Wv[h0 + t * 4];

  const int w = t >> 6;
  const int iL = t & 7;
  const int jL = (t >> 3) & 7;
  const int ti = (w & 1) * 8 + iL;   // 0..15 -> i = i0 + ti*2 + r
  const int tj = (w >> 1) * 8 + jL;  // 0..15 -> j = j0 + tj*4 + c
  const int qi = t >> 3;             // staging row 0..31
  const int qh = (t & 7) * 4;        // staging col

  float acc[2][4] = {};
  for (int hc = 0; hc < 2; ++hc) {
    __syncthreads();
    vf4 qv = *(const vf4*)&Qp[(((b << 8) + i0 + qi) << 8) + h0 + hc * 32 + qh];
    *(vf4*)&Qs[qi * 36 + qh] = qv;
#pragma unroll
    for (int s = 0; s < 2; ++s) {
      const int kj = qi + s * 32;
      vf4 kv = *(const vf4*)&Kp[(((b << 8) + j0 + kj) << 8) + h0 + hc * 32 + qh];
#pragma unroll
      for (int e = 0; e < 4; ++e) Kt[(qh + e) * 68 + kj] = kv[e];
    }
    __syncthreads();
#pragma unroll
    for (int hh = 0; hh < 8; ++hh) {
      vf4 wv4 = *(const vf4*)&wvs[hc * 32 + hh * 4];
      vf4 q0 = *(const vf4*)&Qs[(ti * 2 + 0) * 36 + hh * 4];
      vf4 q1 = *(const vf4*)&Qs[(ti * 2 + 1) * 36 + hh * 4];
#pragma unroll
      for (int e = 0; e < 4; ++e) {
        vf4 kj4 = *(const vf4*)&Kt[(hh * 4 + e) * 68 + tj * 4];
        const float we = wv4[e];
#pragma unroll
        for (int c = 0; c < 4; ++c) {
          acc[0][c] += we * frcp(fexp2(q0[e] + kj4[c]) + 1.0f);
          acc[1][c] += we * frcp(fexp2(q1[e] + kj4[c]) + 1.0f);
        }
      }
    }
  }
  float* base = P + (((hp * 8 + b) * 256 + j0) << 8) + i0;
#pragma unroll
  for (int c = 0; c < 4; ++c) {
    vf2 o = {acc[0][c], acc[1][c]};
    *(vf2*)&base[(tj * 4 + c) * 256 + ti * 2] = o;
  }
}

// ---------------------------------------------------------------------------
// Kernel 3: combine partials + mask + softmax over i (axis=1). Wave per
// (b,j) row; 256 i = 4/lane. score = Swv - 2*sum_p P[p]; masked rows -> 1/256.
__global__ __launch_bounds__(256) void combine_softmax_kernel(
    const float* __restrict__ P, const float* __restrict__ Wv,
    const int* __restrict__ valid_lens, float* __restrict__ WT) {
  const int t = threadIdx.x;
  const int l = t & 63;
  const int row = blockIdx.x * 4 + (t >> 6);  // b*256 + j
  const int b = row >> 8;
  const int j = row & 255;

  vf4 w4 = *(const vf4*)&Wv[l * 4];
  float sw = w4[0] + w4[1] + w4[2] + w4[3];
#pragma unroll
  for (int off = 1; off < 64; off <<= 1) sw += __shfl_xor(sw, off, 64);

  vf4 s4 = {0.f, 0.f, 0.f, 0.f};
#pragma unroll
  for (int hp = 0; hp < 4; ++hp)
    s4 += *(const vf4*)&P[(((hp * 8 + b) * 256 + j) << 8) + l * 4];

  const bool masked = (j >= valid_lens[b]);
  vf4 sc;
#pragma unroll
  for (int c = 0; c < 4; ++c) sc[c] = masked ? MASKV : (sw - 2.0f * s4[c]);

  float m = fmaxf(fmaxf(sc[0], sc[1]), fmaxf(sc[2], sc[3]));
#pragma unroll
  for (int off = 1; off < 64; off <<= 1) m = fmaxf(m, __shfl_xor(m, off, 64));
  vf4 e;
  float es = 0.f;
#pragma unroll
  for (int c = 0; c < 4; ++c) { e[c] = fexp2((sc[c] - m) * LOG2E); es += e[c]; }
#pragma unroll
  for (int off = 1; off < 64; off <<= 1) es += __shfl_xor(es, off, 64);
  const float r = frcp(es);
#pragma unroll
  for (int c = 0; c < 4; ++c) e[c] *= r;
  *(vf4*)&WT[(row << 8) + l * 4] = e;
}

// ---------------------------------------------------------------------------
// Kernel 4: out partial GEMM. out[b,i,d] = sum_j WT[b][j][i] * V[b][j][d].
// Both operands j(k)-major -> b128 outer-product staging. Tile 64i x 64d,
// 4x4/thread, j-split x2 (grid 256 -> 4 waves/CU). O2[js] partial buffers.
__global__ __launch_bounds__(256) void out_part_kernel(
    const float* __restrict__ WT, const float* __restrict__ V,
    float* __restrict__ O2) {
  __shared__ alignas(16) float As[32 * 68];  // [j][i]
  __shared__ alignas(16) float Bs[32 * 68];  // [j][d]
  const int t = threadIdx.x;
  const int d0 = (blockIdx.x & 3) * 64;
  const int js = blockIdx.x >> 2;
  const int i0 = blockIdx.y * 64;
  const int b = blockIdx.z;
  const int w = t >> 6;
  const int ti = (w & 1) * 8 + (t & 7);         // i = i0 + ti*4 + ii
  const int td = (w >> 1) * 8 + ((t >> 3) & 7); // d = d0 + td*4 + dd
  const int sr = t >> 3, sc4 = (t & 7) * 4;

  float acc[4][4] = {};
  for (int jc = 0; jc < 4; ++jc) {
    const int jbase = js * 128 + jc * 32;
    __syncthreads();
#pragma unroll
    for (int s = 0; s < 2; ++s) {
      const int col = sc4 + s * 32;
      *(vf4*)&As[sr * 68 + col] =
          *(const vf4*)&WT[(((b << 8) + jbase + sr) << 8) + i0 + col];
      *(vf4*)&Bs[sr * 68 + col] =
          *(const vf4*)&V[(((b << 8) + jbase + sr) << 8) + d0 + col];
    }
    __syncthreads();
#pragma unroll
    for (int jj = 0; jj < 32; ++jj) {
      vf4 a4 = *(const vf4*)&As[jj * 68 + ti * 4];
      vf4 b4 = *(const vf4*)&Bs[jj * 68 + td * 4];
#pragma unroll
      for (int i = 0; i < 4; ++i)
#pragma unroll
        for (int d = 0; d < 4; ++d) acc[i][d] += a4[i] * b4[d];
    }
  }
  float* O = O2 + js * 524288;
#pragma unroll
  for (int i = 0; i < 4; ++i) {
    vf4 o = {acc[i][0], acc[i][1], acc[i][2], acc[i][3]};
    *(vf4*)&O[(((b << 8) + i0 + ti * 4 + i) << 8) + d0 + td * 4] = o;
  }
}

// ---------------------------------------------------------------------------
// Kernel 5: sum the two out partials.
__global__ __launch_bounds__(256) void out_sum_kernel(
    const float* __restrict__ O2, float* __restrict__ out) {
  const int idx = (blockIdx.x * 256 + threadIdx.x) * 4;
  vf4 a = *(const vf4*)&O2[idx];
  vf4 b = *(const vf4*)&O2[524288 + idx];
  *(vf4*)&out[idx] = a + b;
}

// ---------------------------------------------------------------------------
extern "C" void kernel_launch(void* const* d_in, const int* in_sizes, int n_in,
                              void* d_out, int out_size, void* d_ws, size_t ws_size,
                              hipStream_t stream) {
  const float* queries = (const float*)d_in[0];
  const float* keyes = (const float*)d_in[1];
  const float* values = (const float*)d_in[2];
  const int* valid_lens = (const int*)d_in[3];
  const float* Wq = (const float*)d_in[4];
  const float* Wk = (const float*)d_in[5];
  const float* Wv = (const float*)d_in[6];
  float* out = (float*)d_out;

  float* Qp = (float*)d_ws;          // 2 MB
  float* Kp = Qp + 524288;           // 2 MB
  float* P  = Kp + 524288;           // 8 MB, [hp][b][j][i]
  float* WT = P + 4 * 524288;        // 2 MB, [b][j][i]
  float* O2 = WT + 524288;           // 4 MB, [js][b][i][d]

  proj_kernel<<<dim3(64, 4), 256, 0, stream>>>(queries, keyes, Wq, Wk, Qp, Kp);
  scores_part_kernel<<<dim3(32, 4, 8), 256, 0, stream>>>(Qp, Kp, Wv, P);
  combine_softmax_kernel<<<512, 256, 0, stream>>>(P, Wv, valid_lens, WT);
  out_part_kernel<<<dim3(8, 4, 8), 256, 0, stream>>>(WT, values, O2);
  out_sum_kernel<<<512, 256, 0, stream>>>(O2, out);
}